// Round 5
// baseline (1148.479 us; speedup 1.0000x reference)
//
#include <hip/hip_runtime.h>

#define NPTS 100000
#define CC   64
#define KK   27
#define TOT  (KK * NPTS)        // 2,700,000 edges
#define EPSBN 1e-5f
#define MT   128                // dst rows per conv block
#define NB   ((NPTS + MT - 1) / MT)   // 782 dst-blocks (= buckets per k)

#define CHUNK  12500            // edges per partition block (divides NPTS)
#define NCHK   (NPTS / CHUNK)   // 8 chunks per k-slice
#define NCH    (TOT / CHUNK)    // 216 chunks total

#define XBLK   (NPTS * CC / 1024)       // 6250 blocks for x conversion
#define WBLK   (2 * KK * CC * CC / 256) // 864 blocks for W prep

// fixed-point scale for the LDS integer accumulator (ds_add_u32 is native;
// fp32 LDS atomicAdd compiles to a CAS retry loop -> 7x slowdown, round 1)
#define FPSCALE 262144.0f               // 2^18
#define FPINV   3.814697265625e-06f     // 2^-18
#define FPMAGIC 12582912.0f             // 1.5 * 2^23
#define FPBITS  0x4B400000

typedef float          f32x4  __attribute__((ext_vector_type(4)));
typedef short          bf16x8 __attribute__((ext_vector_type(8)));
typedef unsigned int   u32x4  __attribute__((ext_vector_type(4)));
typedef unsigned short u16x4  __attribute__((ext_vector_type(4)));
typedef int            i32x4  __attribute__((ext_vector_type(4)));

__device__ __forceinline__ unsigned short f2bf(float f) {
    unsigned int u = __float_as_uint(f);
    u = (u + 0x7fffu + ((u >> 16) & 1u)) >> 16;
    return (unsigned short)u;
}

__device__ __forceinline__ int f2fix(float v) {
    return __float_as_int(fmaf(v, FPSCALE, FPMAGIC)) - FPBITS;
}

// ---------------- prep: x -> bf16 (blocks [0,XBLK)) + W -> Wt (blocks [XBLK,..)) ----
__global__ void k_prep(const float* __restrict__ x,
                       const float* __restrict__ W1, const float* __restrict__ W2,
                       unsigned short* __restrict__ xb,
                       unsigned short* __restrict__ Wt1, unsigned short* __restrict__ Wt2) {
    int b = blockIdx.x;
    if (b < XBLK) {
        int id = b * 256 + threadIdx.x;
        f32x4 v = ((const f32x4*)x)[id];
        u16x4 o;
#pragma unroll
        for (int j = 0; j < 4; ++j) o[j] = f2bf(v[j]);
        ((u16x4*)xb)[id] = o;
    } else {
        int id = (b - XBLK) * 256 + threadIdx.x;
        int which = id / (KK * CC * CC);
        int r = id % (KK * CC * CC);
        int k = r / (CC * CC);
        int rem = r % (CC * CC);
        int cin = rem / CC, cout = rem % CC;
        const float* W = which ? W2 : W1;
        unsigned short* Wt = which ? Wt2 : Wt1;
        Wt[k * CC * CC + cout * CC + cin] = f2bf(W[r]);
    }
}

// ---------------- CSR build: per-(k, dst-block) buckets, order-free ----------------
__global__ __launch_bounds__(256) void k_hist(const int* __restrict__ out_idx,
                                              int* __restrict__ ccnt) {
    __shared__ int lc[NB];
    const int t = threadIdx.x;
    for (int i = t; i < NB; i += 256) lc[i] = 0;
    __syncthreads();
    const i32x4* src = (const i32x4*)(out_idx + blockIdx.x * CHUNK);
    for (int ii = t; ii < CHUNK / 4; ii += 256) {
        i32x4 d = src[ii];
#pragma unroll
        for (int q = 0; q < 4; ++q) atomicAdd(&lc[d[q] >> 7], 1);
    }
    __syncthreads();
    for (int i = t; i < NB; i += 256) ccnt[blockIdx.x * NB + i] = lc[i];
}

__global__ __launch_bounds__(256) void k_scan(const int* __restrict__ ccnt,
                                              int* __restrict__ rbase,
                                              int* __restrict__ cbase) {
    __shared__ int tl[NB];
    __shared__ int psum[256];
    const int t = threadIdx.x;
    const int k = blockIdx.x;
    for (int b = t; b < NB; b += 256) {
        int s = 0;
#pragma unroll
        for (int c = 0; c < NCHK; ++c) s += ccnt[(k * NCHK + c) * NB + b];
        tl[b] = s;
    }
    __syncthreads();
    int vals[4];
    int s = 0;
#pragma unroll
    for (int q = 0; q < 4; ++q) {
        int b = t * 4 + q;
        int v = (b < NB) ? tl[b] : 0;
        vals[q] = v; s += v;
    }
    psum[t] = s;
    __syncthreads();
    for (int o = 1; o < 256; o <<= 1) {
        int pv = (t >= o) ? psum[t - o] : 0;
        __syncthreads();
        psum[t] += pv;
        __syncthreads();
    }
    int run = k * NPTS + (t ? psum[t - 1] : 0);
#pragma unroll
    for (int q = 0; q < 4; ++q) {
        int b = t * 4 + q;
        if (b < NB) {
            rbase[k * NB + b] = run;
            int r2 = run;
#pragma unroll
            for (int c = 0; c < NCHK; ++c) {
                cbase[(k * NCHK + c) * NB + b] = r2;
                r2 += ccnt[(k * NCHK + c) * NB + b];
            }
            run += vals[q];
        }
    }
    if (k == 0 && t == 0) rbase[KK * NB] = TOT;
}

__global__ __launch_bounds__(256) void k_part(
    const int* __restrict__ out_idx, const int* __restrict__ in_idx,
    const int* __restrict__ cbase, unsigned* __restrict__ entries) {
    __shared__ int lcur[NB];
    const int t = threadIdx.x;
    for (int i = t; i < NB; i += 256) lcur[i] = cbase[blockIdx.x * NB + i];
    __syncthreads();
    const int j0 = blockIdx.x * CHUNK;
    const i32x4* dsrc = (const i32x4*)(out_idx + j0);
    const i32x4* ssrc = (const i32x4*)(in_idx + j0);
    for (int ii = t; ii < CHUNK / 4; ii += 256) {
        i32x4 d4 = dsrc[ii];
        i32x4 s4 = ssrc[ii];
#pragma unroll
        for (int q = 0; q < 4; ++q) {
            int d = d4[q];
            int pos = atomicAdd(&lcur[d >> 7], 1);
            entries[pos] = ((unsigned)(d & 127) << 17) | (unsigned)s4[q];
        }
    }
}

// ---------------- conv: edge-dense MFMA tiles + fixed-point LDS scatter ------------
// 512 threads = 8 waves/block: grid is only 782 blocks (3 blocks/CU), so occupancy
// comes from waves-per-block (round 4 measured 24% at 4 waves -> grid-geometry bound).
// Wave w handles k = w, w+8, ... ; per k, 32-edge tiles: rows = edge slots.
// 2-deep gather-index pipeline. No __syncthreads in the main loop.
// launch_bounds(512,6): VGPR cap ~85 >= the ~64 this kernel needs -- NEVER set a
// bound the allocator can't meet ((256,5) spilled ~140 MB scratch, round 3).
__global__ __launch_bounds__(512, 6) void k_conv(
    const unsigned short* __restrict__ xb,    // [N][64] bf16
    const unsigned short* __restrict__ Wt,    // [27][cout=64][cin=64] bf16
    const int* __restrict__ rbase,            // [KK*NB+1] bucket starts
    const unsigned* __restrict__ entries,     // [TOT]: (dloc7<<17)|src17
    float* __restrict__ y,                    // [N][64] fp32
    float* __restrict__ sums)                 // [128]: sum, sumsq per channel
{
    __shared__ int ylds[MT * 64];             // 32768 B -> 5 blocks/CU LDS-wise

    const int tid  = threadIdx.x;
    const int lane = tid & 63;
    const int wave = tid >> 6;                // 0..7
    const int quad = lane >> 4;
    const int l16  = lane & 15;
    const int blk  = blockIdx.x;
    const int i0   = blk << 7;

    for (int i = tid; i < MT * 64; i += 512) ylds[i] = 0;
    __syncthreads();

    const unsigned short* xq = xb + quad * 8;

    for (int k = wave; k < KK; k += 8) {
        const int start = rbase[k * NB + blk];
        const int E     = rbase[k * NB + blk + 1] - start;
        if (E == 0) continue;
        const int emax = E - 1;

        // B fragments straight from global Wt (221 KB total, L2-hot)
        bf16x8 bfr[4][2];
        const unsigned short* wk = Wt + k * (CC * CC) + l16 * CC + quad * 8;
#pragma unroll
        for (int nt = 0; nt < 4; ++nt) {
            bfr[nt][0] = *(const bf16x8*)(wk + nt * 16 * CC);
            bfr[nt][1] = *(const bf16x8*)(wk + nt * 16 * CC + 32);
        }

        const int ntile = (E + 31) >> 5;

        // prologue: indices + gather for tile 0, indices for tile 1
        unsigned egA = entries[start + min(l16, emax)];
        unsigned egB = entries[start + min(16 + l16, emax)];
        bf16x8 cfr[2][2];
        {
            const unsigned short* p0 = xq + (egA & 0x1FFFFu) * CC;
            const unsigned short* p1 = xq + (egB & 0x1FFFFu) * CC;
            cfr[0][0] = *(const bf16x8*)p0;
            cfr[0][1] = *(const bf16x8*)(p0 + 32);
            cfr[1][0] = *(const bf16x8*)p1;
            cfr[1][1] = *(const bf16x8*)(p1 + 32);
        }
        unsigned egA1 = entries[start + min(32 + l16, emax)];
        unsigned egB1 = entries[start + min(48 + l16, emax)];

        for (int t = 0; t < ntile; ++t) {
            const int tb = t * 32;
            // scatter-row entries for THIS tile (quad-broadcast, L1-hot)
            unsigned dp[2][4];
#pragma unroll
            for (int mt = 0; mt < 2; ++mt)
#pragma unroll
                for (int rr = 0; rr < 4; ++rr)
                    dp[mt][rr] = entries[start + min(tb + mt * 16 + quad * 4 + rr, emax)];
            // gather tile t+1's A fragments from RESIDENT indices (no chained latency)
            bf16x8 nfr[2][2];
            {
                const unsigned short* p0 = xq + (egA1 & 0x1FFFFu) * CC;
                const unsigned short* p1 = xq + (egB1 & 0x1FFFFu) * CC;
                nfr[0][0] = *(const bf16x8*)p0;
                nfr[0][1] = *(const bf16x8*)(p0 + 32);
                nfr[1][0] = *(const bf16x8*)p1;
                nfr[1][1] = *(const bf16x8*)(p1 + 32);
            }
            // prefetch indices for tile t+2
            unsigned egA2 = entries[start + min(tb + 64 + l16, emax)];
            unsigned egB2 = entries[start + min(tb + 80 + l16, emax)];

            f32x4 acc[2][4];
#pragma unroll
            for (int mt = 0; mt < 2; ++mt)
#pragma unroll
                for (int nt = 0; nt < 4; ++nt) acc[mt][nt] = (f32x4){0.f, 0.f, 0.f, 0.f};
            __builtin_amdgcn_s_setprio(1);
#pragma unroll
            for (int mt = 0; mt < 2; ++mt)
#pragma unroll
                for (int nt = 0; nt < 4; ++nt) {
                    acc[mt][nt] = __builtin_amdgcn_mfma_f32_16x16x32_bf16(
                        cfr[mt][0], bfr[nt][0], acc[mt][nt], 0, 0, 0);
                    acc[mt][nt] = __builtin_amdgcn_mfma_f32_16x16x32_bf16(
                        cfr[mt][1], bfr[nt][1], acc[mt][nt], 0, 0, 0);
                }
            __builtin_amdgcn_s_setprio(0);

            // scatter: 32 native ds_add_u32 per lane per tile (fixed-point, swizzled)
#pragma unroll
            for (int mt = 0; mt < 2; ++mt)
#pragma unroll
                for (int rr = 0; rr < 4; ++rr) {
                    int slot = tb + mt * 16 + quad * 4 + rr;
                    if (slot < E) {
                        int row = (int)(dp[mt][rr] >> 17);
                        int xv = (row & 1) << 4;
                        unsigned* yp = (unsigned*)&ylds[row * 64 + l16];
                        atomicAdd(yp + (0 ^ xv),  (unsigned)f2fix(acc[mt][0][rr]));
                        atomicAdd(yp + (16 ^ xv), (unsigned)f2fix(acc[mt][1][rr]));
                        atomicAdd(yp + (32 ^ xv), (unsigned)f2fix(acc[mt][2][rr]));
                        atomicAdd(yp + (48 ^ xv), (unsigned)f2fix(acc[mt][3][rr]));
                    }
                }
            cfr[0][0] = nfr[0][0]; cfr[0][1] = nfr[0][1];
            cfr[1][0] = nfr[1][0]; cfr[1][1] = nfr[1][1];
            egA1 = egA2; egB1 = egB2;
        }
    }
    __syncthreads();

    // epilogue: write y + fused BN partial sums (ylds reused as scratch after reads)
    const int col = tid & 63;
    const int rg  = tid >> 6;                 // 0..7 -> 16 rows each
    float s = 0.f, q = 0.f;
#pragma unroll
    for (int i = 0; i < 16; ++i) {
        int row = rg * 16 + i;
        float v = (float)ylds[row * 64 + (col ^ ((row & 1) << 4))] * FPINV;
        int gr = i0 + row;
        if (gr < NPTS) y[(long)gr * CC + col] = v;
        s += v; q += v * v;
    }
    __syncthreads();                      // all ylds reads done
    float* ps = (float*)ylds;
    ps[rg * 128 + col] = s;
    ps[rg * 128 + 64 + col] = q;
    __syncthreads();
    if (tid < 128) {
        int which = tid >> 6, c = tid & 63;
        float a = 0.f;
#pragma unroll
        for (int wv = 0; wv < 8; ++wv) a += ps[wv * 128 + which * 64 + c];
        atomicAdd(&sums[which * 64 + c], a);
    }
}

// ---------------- a1 = bf16(relu(y*s + b)) with inline BN finalize ----------------
__global__ void k_apply(const float* __restrict__ y, const float* __restrict__ sums,
                        const float* __restrict__ gamma, const float* __restrict__ beta,
                        unsigned short* __restrict__ ab) {
    __shared__ float sb[128];
    int t = threadIdx.x;
    if (t < 64) {
        float mu  = sums[t] * (1.0f / NPTS);
        float var = sums[t + 64] * (1.0f / NPTS) - mu * mu;
        float s = gamma[t] * rsqrtf(var + EPSBN);
        sb[t] = s;
        sb[t + 64] = beta[t] - mu * s;
    }
    __syncthreads();
    int id = blockIdx.x * 256 + t;
    f32x4 v = ((const f32x4*)y)[id];
    int c0 = (id * 4) & 63;
    u16x4 o;
#pragma unroll
    for (int j = 0; j < 4; ++j) {
        float r = fmaxf(v[j] * sb[c0 + j] + sb[64 + c0 + j], 0.f);
        o[j] = f2bf(r);
    }
    ((u16x4*)ab)[id] = o;
}

// ---------------- out = relu(y*s + b + x) with inline BN finalize ----------------
__global__ void k_final(const float* __restrict__ y, const float* __restrict__ x,
                        const float* __restrict__ sums,
                        const float* __restrict__ gamma, const float* __restrict__ beta,
                        float* __restrict__ out) {
    __shared__ float sb[128];
    int t = threadIdx.x;
    if (t < 64) {
        float mu  = sums[t] * (1.0f / NPTS);
        float var = sums[t + 64] * (1.0f / NPTS) - mu * mu;
        float s = gamma[t] * rsqrtf(var + EPSBN);
        sb[t] = s;
        sb[t + 64] = beta[t] - mu * s;
    }
    __syncthreads();
    int id = blockIdx.x * 256 + t;
    f32x4 v  = ((const f32x4*)y)[id];
    f32x4 xv = ((const f32x4*)x)[id];
    int c0 = (id * 4) & 63;
    f32x4 o;
#pragma unroll
    for (int j = 0; j < 4; ++j)
        o[j] = fmaxf(v[j] * sb[c0 + j] + sb[64 + c0 + j] + xv[j], 0.f);
    ((f32x4*)out)[id] = o;
}

extern "C" void kernel_launch(void* const* d_in, const int* in_sizes, int n_in,
                              void* d_out, int out_size, void* d_ws, size_t ws_size,
                              hipStream_t stream) {
    const float* x      = (const float*)d_in[0];
    // d_in[1] = norm_points (unused by the reference math)
    const float* W1     = (const float*)d_in[2];
    const float* gamma1 = (const float*)d_in[3];
    const float* beta1  = (const float*)d_in[4];
    const float* W2     = (const float*)d_in[5];
    const float* gamma2 = (const float*)d_in[6];
    const float* beta2  = (const float*)d_in[7];
    const int* in_idx   = (const int*)d_in[8];
    const int* out_idx  = (const int*)d_in[9];
    float* out = (float*)d_out;

    char* w = (char*)d_ws;
    size_t off = 0;
    auto alloc = [&](size_t bytes) -> char* {
        off = (off + 255) & ~(size_t)255;
        char* p = w + off;
        off += bytes;
        return p;
    };
    float* sums      = (float*)   alloc(256 * 4);   // [0:128) layer1, [128:256) layer2
    int*   ccnt      = (int*)     alloc((size_t)NCH * NB * 4);
    int*   cbase     = (int*)     alloc((size_t)NCH * NB * 4);
    int*   rbase     = (int*)     alloc(((size_t)KK * NB + 1) * 4);
    unsigned* entries = (unsigned*)alloc((size_t)TOT * 4);
    unsigned short* xbf = (unsigned short*)alloc((size_t)NPTS * CC * 2);
    unsigned short* Wt1 = (unsigned short*)alloc((size_t)KK * CC * CC * 2);
    unsigned short* Wt2 = (unsigned short*)alloc((size_t)KK * CC * CC * 2);
    float* y = (float*)alloc((size_t)NPTS * CC * 4);

    hipMemsetAsync(sums, 0, 256 * 4, stream);

    k_prep<<<XBLK + WBLK, 256, 0, stream>>>(x, W1, W2, xbf, Wt1, Wt2);
    k_hist<<<NCH, 256, 0, stream>>>(out_idx, ccnt);
    k_scan<<<KK, 256, 0, stream>>>(ccnt, rbase, cbase);
    k_part<<<NCH, 256, 0, stream>>>(out_idx, in_idx, cbase, entries);

    k_conv<<<NB, 512, 0, stream>>>(xbf, Wt1, rbase, entries, y, sums);
    k_apply<<<NPTS * CC / 1024, 256, 0, stream>>>(y, sums, gamma1, beta1, xbf);  // a1 -> xbf
    k_conv<<<NB, 512, 0, stream>>>(xbf, Wt2, rbase, entries, y, sums + 128);
    k_final<<<NPTS * CC / 1024, 256, 0, stream>>>(y, x, sums + 128, gamma2, beta2, out);
}

// Round 6
// 380.121 us; speedup vs baseline: 3.0213x; 3.0213x over previous
//
#include <hip/hip_runtime.h>

#define NPTS 100000
#define CC   64
#define KK   27
#define TOT  (KK * NPTS)        // 2,700,000 edges
#define EPSBN 1e-5f
#define MT   128                // dst rows per conv block
#define NB   ((NPTS + MT - 1) / MT)   // 782 dst-blocks (= buckets per k)

#define CHUNK  12500            // edges per partition block (divides NPTS)
#define NCHK   (NPTS / CHUNK)   // 8 chunks per k-slice
#define NCH    (TOT / CHUNK)    // 216 chunks total

#define XBLK   (NPTS * CC / 1024)       // 6250 blocks for x conversion
#define WBLK   (2 * KK * CC * CC / 256) // 864 blocks for W prep

// fixed-point scale for the LDS integer accumulator (ds_add_u32 is native;
// fp32 LDS atomicAdd compiles to a CAS retry loop -> 7x slowdown, round 1)
#define FPSCALE 262144.0f               // 2^18
#define FPINV   3.814697265625e-06f     // 2^-18
#define FPMAGIC 12582912.0f             // 1.5 * 2^23
#define FPBITS  0x4B400000

typedef float          f32x4  __attribute__((ext_vector_type(4)));
typedef short          bf16x8 __attribute__((ext_vector_type(8)));
typedef unsigned int   u32x4  __attribute__((ext_vector_type(4)));
typedef unsigned short u16x4  __attribute__((ext_vector_type(4)));
typedef int            i32x4  __attribute__((ext_vector_type(4)));

__device__ __forceinline__ unsigned short f2bf(float f) {
    unsigned int u = __float_as_uint(f);
    u = (u + 0x7fffu + ((u >> 16) & 1u)) >> 16;
    return (unsigned short)u;
}

__device__ __forceinline__ int f2fix(float v) {
    return __float_as_int(fmaf(v, FPSCALE, FPMAGIC)) - FPBITS;
}

// ---------------- prep: x -> bf16 (blocks [0,XBLK)) + W -> Wt (blocks [XBLK,..)) ----
__global__ void k_prep(const float* __restrict__ x,
                       const float* __restrict__ W1, const float* __restrict__ W2,
                       unsigned short* __restrict__ xb,
                       unsigned short* __restrict__ Wt1, unsigned short* __restrict__ Wt2) {
    int b = blockIdx.x;
    if (b < XBLK) {
        int id = b * 256 + threadIdx.x;
        f32x4 v = ((const f32x4*)x)[id];
        u16x4 o;
#pragma unroll
        for (int j = 0; j < 4; ++j) o[j] = f2bf(v[j]);
        ((u16x4*)xb)[id] = o;
    } else {
        int id = (b - XBLK) * 256 + threadIdx.x;
        int which = id / (KK * CC * CC);
        int r = id % (KK * CC * CC);
        int k = r / (CC * CC);
        int rem = r % (CC * CC);
        int cin = rem / CC, cout = rem % CC;
        const float* W = which ? W2 : W1;
        unsigned short* Wt = which ? Wt2 : Wt1;
        Wt[k * CC * CC + cout * CC + cin] = f2bf(W[r]);
    }
}

// ---------------- CSR build: per-(k, dst-block) buckets, order-free ----------------
__global__ __launch_bounds__(256) void k_hist(const int* __restrict__ out_idx,
                                              int* __restrict__ ccnt) {
    __shared__ int lc[NB];
    const int t = threadIdx.x;
    for (int i = t; i < NB; i += 256) lc[i] = 0;
    __syncthreads();
    const i32x4* src = (const i32x4*)(out_idx + blockIdx.x * CHUNK);
    for (int ii = t; ii < CHUNK / 4; ii += 256) {
        i32x4 d = src[ii];
#pragma unroll
        for (int q = 0; q < 4; ++q) atomicAdd(&lc[d[q] >> 7], 1);
    }
    __syncthreads();
    for (int i = t; i < NB; i += 256) ccnt[blockIdx.x * NB + i] = lc[i];
}

__global__ __launch_bounds__(256) void k_scan(const int* __restrict__ ccnt,
                                              int* __restrict__ rbase,
                                              int* __restrict__ cbase) {
    __shared__ int tl[NB];
    __shared__ int psum[256];
    const int t = threadIdx.x;
    const int k = blockIdx.x;
    for (int b = t; b < NB; b += 256) {
        int s = 0;
#pragma unroll
        for (int c = 0; c < NCHK; ++c) s += ccnt[(k * NCHK + c) * NB + b];
        tl[b] = s;
    }
    __syncthreads();
    int vals[4];
    int s = 0;
#pragma unroll
    for (int q = 0; q < 4; ++q) {
        int b = t * 4 + q;
        int v = (b < NB) ? tl[b] : 0;
        vals[q] = v; s += v;
    }
    psum[t] = s;
    __syncthreads();
    for (int o = 1; o < 256; o <<= 1) {
        int pv = (t >= o) ? psum[t - o] : 0;
        __syncthreads();
        psum[t] += pv;
        __syncthreads();
    }
    int run = k * NPTS + (t ? psum[t - 1] : 0);
#pragma unroll
    for (int q = 0; q < 4; ++q) {
        int b = t * 4 + q;
        if (b < NB) {
            rbase[k * NB + b] = run;
            int r2 = run;
#pragma unroll
            for (int c = 0; c < NCHK; ++c) {
                cbase[(k * NCHK + c) * NB + b] = r2;
                r2 += ccnt[(k * NCHK + c) * NB + b];
            }
            run += vals[q];
        }
    }
    if (k == 0 && t == 0) rbase[KK * NB] = TOT;
}

__global__ __launch_bounds__(256) void k_part(
    const int* __restrict__ out_idx, const int* __restrict__ in_idx,
    const int* __restrict__ cbase, unsigned* __restrict__ entries) {
    __shared__ int lcur[NB];
    const int t = threadIdx.x;
    for (int i = t; i < NB; i += 256) lcur[i] = cbase[blockIdx.x * NB + i];
    __syncthreads();
    const int j0 = blockIdx.x * CHUNK;
    const i32x4* dsrc = (const i32x4*)(out_idx + j0);
    const i32x4* ssrc = (const i32x4*)(in_idx + j0);
    for (int ii = t; ii < CHUNK / 4; ii += 256) {
        i32x4 d4 = dsrc[ii];
        i32x4 s4 = ssrc[ii];
#pragma unroll
        for (int q = 0; q < 4; ++q) {
            int d = d4[q];
            int pos = atomicAdd(&lcur[d >> 7], 1);
            entries[pos] = ((unsigned)(d & 127) << 17) | (unsigned)s4[q];
        }
    }
}

// ---------------- conv: edge-dense MFMA tiles + fixed-point LDS scatter ------------
// 512 threads = 8 waves/block: grid is only 782 blocks (3 blocks/CU), so occupancy
// comes from waves-per-block. Wave w handles k = w, w+8, ...
// 2-deep gather-index pipeline. No __syncthreads in the main loop.
// launch_bounds(512,4): VGPR cap 128 >= the ~64 this kernel needs.
// NEVER set a waves/EU bound the allocator can't meet: (256,5) -> 48 VGPR,
// 140 MB scratch (round 3); (512,6) -> 40 VGPR, 1.4 GB scratch (round 5).
__global__ __launch_bounds__(512, 4) void k_conv(
    const unsigned short* __restrict__ xb,    // [N][64] bf16
    const unsigned short* __restrict__ Wt,    // [27][cout=64][cin=64] bf16
    const int* __restrict__ rbase,            // [KK*NB+1] bucket starts
    const unsigned* __restrict__ entries,     // [TOT]: (dloc7<<17)|src17
    float* __restrict__ y,                    // [N][64] fp32
    float* __restrict__ sums)                 // [128]: sum, sumsq per channel
{
    __shared__ int ylds[MT * 64];             // 32768 B

    const int tid  = threadIdx.x;
    const int lane = tid & 63;
    const int wave = tid >> 6;                // 0..7
    const int quad = lane >> 4;
    const int l16  = lane & 15;
    const int blk  = blockIdx.x;
    const int i0   = blk << 7;

    for (int i = tid; i < MT * 64; i += 512) ylds[i] = 0;
    __syncthreads();

    const unsigned short* xq = xb + quad * 8;

    for (int k = wave; k < KK; k += 8) {
        const int start = rbase[k * NB + blk];
        const int E     = rbase[k * NB + blk + 1] - start;
        if (E == 0) continue;
        const int emax = E - 1;

        // B fragments straight from global Wt (221 KB total, L2-hot)
        bf16x8 bfr[4][2];
        const unsigned short* wk = Wt + k * (CC * CC) + l16 * CC + quad * 8;
#pragma unroll
        for (int nt = 0; nt < 4; ++nt) {
            bfr[nt][0] = *(const bf16x8*)(wk + nt * 16 * CC);
            bfr[nt][1] = *(const bf16x8*)(wk + nt * 16 * CC + 32);
        }

        const int ntile = (E + 31) >> 5;

        // prologue: indices + gather for tile 0, indices for tile 1
        unsigned egA = entries[start + min(l16, emax)];
        unsigned egB = entries[start + min(16 + l16, emax)];
        bf16x8 cfr[2][2];
        {
            const unsigned short* p0 = xq + (egA & 0x1FFFFu) * CC;
            const unsigned short* p1 = xq + (egB & 0x1FFFFu) * CC;
            cfr[0][0] = *(const bf16x8*)p0;
            cfr[0][1] = *(const bf16x8*)(p0 + 32);
            cfr[1][0] = *(const bf16x8*)p1;
            cfr[1][1] = *(const bf16x8*)(p1 + 32);
        }
        unsigned egA1 = entries[start + min(32 + l16, emax)];
        unsigned egB1 = entries[start + min(48 + l16, emax)];

        for (int t = 0; t < ntile; ++t) {
            const int tb = t * 32;
            // scatter-row entries for THIS tile (quad-broadcast, L1-hot)
            unsigned dp[2][4];
#pragma unroll
            for (int mt = 0; mt < 2; ++mt)
#pragma unroll
                for (int rr = 0; rr < 4; ++rr)
                    dp[mt][rr] = entries[start + min(tb + mt * 16 + quad * 4 + rr, emax)];
            // gather tile t+1's A fragments from RESIDENT indices (no chained latency)
            bf16x8 nfr[2][2];
            {
                const unsigned short* p0 = xq + (egA1 & 0x1FFFFu) * CC;
                const unsigned short* p1 = xq + (egB1 & 0x1FFFFu) * CC;
                nfr[0][0] = *(const bf16x8*)p0;
                nfr[0][1] = *(const bf16x8*)(p0 + 32);
                nfr[1][0] = *(const bf16x8*)p1;
                nfr[1][1] = *(const bf16x8*)(p1 + 32);
            }
            // prefetch indices for tile t+2
            unsigned egA2 = entries[start + min(tb + 64 + l16, emax)];
            unsigned egB2 = entries[start + min(tb + 80 + l16, emax)];

            f32x4 acc[2][4];
#pragma unroll
            for (int mt = 0; mt < 2; ++mt)
#pragma unroll
                for (int nt = 0; nt < 4; ++nt) acc[mt][nt] = (f32x4){0.f, 0.f, 0.f, 0.f};
            __builtin_amdgcn_s_setprio(1);
#pragma unroll
            for (int mt = 0; mt < 2; ++mt)
#pragma unroll
                for (int nt = 0; nt < 4; ++nt) {
                    acc[mt][nt] = __builtin_amdgcn_mfma_f32_16x16x32_bf16(
                        cfr[mt][0], bfr[nt][0], acc[mt][nt], 0, 0, 0);
                    acc[mt][nt] = __builtin_amdgcn_mfma_f32_16x16x32_bf16(
                        cfr[mt][1], bfr[nt][1], acc[mt][nt], 0, 0, 0);
                }
            __builtin_amdgcn_s_setprio(0);

            // scatter: 32 native ds_add_u32 per lane per tile (fixed-point, swizzled)
#pragma unroll
            for (int mt = 0; mt < 2; ++mt)
#pragma unroll
                for (int rr = 0; rr < 4; ++rr) {
                    int slot = tb + mt * 16 + quad * 4 + rr;
                    if (slot < E) {
                        int row = (int)(dp[mt][rr] >> 17);
                        int xv = (row & 1) << 4;
                        unsigned* yp = (unsigned*)&ylds[row * 64 + l16];
                        atomicAdd(yp + (0 ^ xv),  (unsigned)f2fix(acc[mt][0][rr]));
                        atomicAdd(yp + (16 ^ xv), (unsigned)f2fix(acc[mt][1][rr]));
                        atomicAdd(yp + (32 ^ xv), (unsigned)f2fix(acc[mt][2][rr]));
                        atomicAdd(yp + (48 ^ xv), (unsigned)f2fix(acc[mt][3][rr]));
                    }
                }
            cfr[0][0] = nfr[0][0]; cfr[0][1] = nfr[0][1];
            cfr[1][0] = nfr[1][0]; cfr[1][1] = nfr[1][1];
            egA1 = egA2; egB1 = egB2;
        }
    }
    __syncthreads();

    // epilogue: write y + fused BN partial sums (ylds reused as scratch after reads)
    const int col = tid & 63;
    const int rg  = tid >> 6;                 // 0..7 -> 16 rows each
    float s = 0.f, q = 0.f;
#pragma unroll
    for (int i = 0; i < 16; ++i) {
        int row = rg * 16 + i;
        float v = (float)ylds[row * 64 + (col ^ ((row & 1) << 4))] * FPINV;
        int gr = i0 + row;
        if (gr < NPTS) y[(long)gr * CC + col] = v;
        s += v; q += v * v;
    }
    __syncthreads();                      // all ylds reads done
    float* ps = (float*)ylds;
    ps[rg * 128 + col] = s;
    ps[rg * 128 + 64 + col] = q;
    __syncthreads();
    if (tid < 128) {
        int which = tid >> 6, c = tid & 63;
        float a = 0.f;
#pragma unroll
        for (int wv = 0; wv < 8; ++wv) a += ps[wv * 128 + which * 64 + c];
        atomicAdd(&sums[which * 64 + c], a);
    }
}

// ---------------- a1 = bf16(relu(y*s + b)) with inline BN finalize ----------------
__global__ void k_apply(const float* __restrict__ y, const float* __restrict__ sums,
                        const float* __restrict__ gamma, const float* __restrict__ beta,
                        unsigned short* __restrict__ ab) {
    __shared__ float sb[128];
    int t = threadIdx.x;
    if (t < 64) {
        float mu  = sums[t] * (1.0f / NPTS);
        float var = sums[t + 64] * (1.0f / NPTS) - mu * mu;
        float s = gamma[t] * rsqrtf(var + EPSBN);
        sb[t] = s;
        sb[t + 64] = beta[t] - mu * s;
    }
    __syncthreads();
    int id = blockIdx.x * 256 + t;
    f32x4 v = ((const f32x4*)y)[id];
    int c0 = (id * 4) & 63;
    u16x4 o;
#pragma unroll
    for (int j = 0; j < 4; ++j) {
        float r = fmaxf(v[j] * sb[c0 + j] + sb[64 + c0 + j], 0.f);
        o[j] = f2bf(r);
    }
    ((u16x4*)ab)[id] = o;
}

// ---------------- out = relu(y*s + b + x) with inline BN finalize ----------------
__global__ void k_final(const float* __restrict__ y, const float* __restrict__ x,
                        const float* __restrict__ sums,
                        const float* __restrict__ gamma, const float* __restrict__ beta,
                        float* __restrict__ out) {
    __shared__ float sb[128];
    int t = threadIdx.x;
    if (t < 64) {
        float mu  = sums[t] * (1.0f / NPTS);
        float var = sums[t + 64] * (1.0f / NPTS) - mu * mu;
        float s = gamma[t] * rsqrtf(var + EPSBN);
        sb[t] = s;
        sb[t + 64] = beta[t] - mu * s;
    }
    __syncthreads();
    int id = blockIdx.x * 256 + t;
    f32x4 v  = ((const f32x4*)y)[id];
    f32x4 xv = ((const f32x4*)x)[id];
    int c0 = (id * 4) & 63;
    f32x4 o;
#pragma unroll
    for (int j = 0; j < 4; ++j)
        o[j] = fmaxf(v[j] * sb[c0 + j] + sb[64 + c0 + j] + xv[j], 0.f);
    ((f32x4*)out)[id] = o;
}

extern "C" void kernel_launch(void* const* d_in, const int* in_sizes, int n_in,
                              void* d_out, int out_size, void* d_ws, size_t ws_size,
                              hipStream_t stream) {
    const float* x      = (const float*)d_in[0];
    // d_in[1] = norm_points (unused by the reference math)
    const float* W1     = (const float*)d_in[2];
    const float* gamma1 = (const float*)d_in[3];
    const float* beta1  = (const float*)d_in[4];
    const float* W2     = (const float*)d_in[5];
    const float* gamma2 = (const float*)d_in[6];
    const float* beta2  = (const float*)d_in[7];
    const int* in_idx   = (const int*)d_in[8];
    const int* out_idx  = (const int*)d_in[9];
    float* out = (float*)d_out;

    char* w = (char*)d_ws;
    size_t off = 0;
    auto alloc = [&](size_t bytes) -> char* {
        off = (off + 255) & ~(size_t)255;
        char* p = w + off;
        off += bytes;
        return p;
    };
    float* sums      = (float*)   alloc(256 * 4);   // [0:128) layer1, [128:256) layer2
    int*   ccnt      = (int*)     alloc((size_t)NCH * NB * 4);
    int*   cbase     = (int*)     alloc((size_t)NCH * NB * 4);
    int*   rbase     = (int*)     alloc(((size_t)KK * NB + 1) * 4);
    unsigned* entries = (unsigned*)alloc((size_t)TOT * 4);
    unsigned short* xbf = (unsigned short*)alloc((size_t)NPTS * CC * 2);
    unsigned short* Wt1 = (unsigned short*)alloc((size_t)KK * CC * CC * 2);
    unsigned short* Wt2 = (unsigned short*)alloc((size_t)KK * CC * CC * 2);
    float* y = (float*)alloc((size_t)NPTS * CC * 4);

    hipMemsetAsync(sums, 0, 256 * 4, stream);

    k_prep<<<XBLK + WBLK, 256, 0, stream>>>(x, W1, W2, xbf, Wt1, Wt2);
    k_hist<<<NCH, 256, 0, stream>>>(out_idx, ccnt);
    k_scan<<<KK, 256, 0, stream>>>(ccnt, rbase, cbase);
    k_part<<<NCH, 256, 0, stream>>>(out_idx, in_idx, cbase, entries);

    k_conv<<<NB, 512, 0, stream>>>(xbf, Wt1, rbase, entries, y, sums);
    k_apply<<<NPTS * CC / 1024, 256, 0, stream>>>(y, sums, gamma1, beta1, xbf);  // a1 -> xbf
    k_conv<<<NB, 512, 0, stream>>>(xbf, Wt2, rbase, entries, y, sums + 128);
    k_final<<<NPTS * CC / 1024, 256, 0, stream>>>(y, x, sums + 128, gamma2, beta2, out);
}

// Round 7
// 366.319 us; speedup vs baseline: 3.1352x; 1.0377x over previous
//
#include <hip/hip_runtime.h>

#define NPTS 100000
#define CC   64
#define KK   27
#define TOT  (KK * NPTS)        // 2,700,000 edges
#define EPSBN 1e-5f
#define MT   128                // dst rows per conv block
#define NB   ((NPTS + MT - 1) / MT)   // 782 dst-blocks (= buckets per k)
#define CAP  200                // bucket capacity: Poisson(128) + 6.4 sigma

#define CHUNK  12500            // edges per partition block (divides NPTS)
#define NCH    (TOT / CHUNK)    // 216 chunks total

#define XBLK   (NPTS * CC / 1024)       // 6250 blocks for x conversion
#define WBLK   (2 * KK * CC * CC / 256) // 864 blocks for W prep

// fixed-point scale for the LDS integer accumulator (ds_add_u32 is native;
// fp32 LDS atomicAdd compiles to a CAS retry loop -> 7x slowdown, round 1)
#define FPSCALE 262144.0f               // 2^18
#define FPINV   3.814697265625e-06f     // 2^-18
#define FPMAGIC 12582912.0f             // 1.5 * 2^23
#define FPBITS  0x4B400000

typedef float          f32x4  __attribute__((ext_vector_type(4)));
typedef short          bf16x8 __attribute__((ext_vector_type(8)));
typedef unsigned int   u32x4  __attribute__((ext_vector_type(4)));
typedef unsigned short u16x4  __attribute__((ext_vector_type(4)));
typedef int            i32x4  __attribute__((ext_vector_type(4)));

__device__ __forceinline__ unsigned short f2bf(float f) {
    unsigned int u = __float_as_uint(f);
    u = (u + 0x7fffu + ((u >> 16) & 1u)) >> 16;
    return (unsigned short)u;
}

__device__ __forceinline__ int f2fix(float v) {
    return __float_as_int(fmaf(v, FPSCALE, FPMAGIC)) - FPBITS;
}

// ---------------- prep: x -> bf16 (blocks [0,XBLK)) + W -> Wt (blocks [XBLK,..)) ----
__global__ void k_prep(const float* __restrict__ x,
                       const float* __restrict__ W1, const float* __restrict__ W2,
                       unsigned short* __restrict__ xb,
                       unsigned short* __restrict__ Wt1, unsigned short* __restrict__ Wt2) {
    int b = blockIdx.x;
    if (b < XBLK) {
        int id = b * 256 + threadIdx.x;
        f32x4 v = ((const f32x4*)x)[id];
        u16x4 o;
#pragma unroll
        for (int j = 0; j < 4; ++j) o[j] = f2bf(v[j]);
        ((u16x4*)xb)[id] = o;
    } else {
        int id = (b - XBLK) * 256 + threadIdx.x;
        int which = id / (KK * CC * CC);
        int r = id % (KK * CC * CC);
        int k = r / (CC * CC);
        int rem = r % (CC * CC);
        int cin = rem / CC, cout = rem % CC;
        const float* W = which ? W2 : W1;
        unsigned short* Wt = which ? Wt2 : Wt1;
        Wt[k * CC * CC + cout * CC + cin] = f2bf(W[r]);
    }
}

// ---------------- single-pass CSR: padded buckets + atomic range reserve ----------
// Bucket (k, dst>>7) lives at entries[(k*NB+b)*CAP ...]; cnt[] holds final counts.
// Per chunk: LDS hist -> one global atomicAdd per bucket reserves a disjoint range
// -> second pass places entries. Replaces the old hist+scan+part triple.
__global__ __launch_bounds__(256) void k_part(
    const int* __restrict__ out_idx, const int* __restrict__ in_idx,
    int* __restrict__ cnt, unsigned* __restrict__ entries) {
    __shared__ int lc[NB];
    const int t = threadIdx.x;
    for (int i = t; i < NB; i += 256) lc[i] = 0;
    __syncthreads();
    const int j0 = blockIdx.x * CHUNK;
    const int k  = j0 / NPTS;                  // CHUNK divides NPTS
    const i32x4* dsrc = (const i32x4*)(out_idx + j0);
    const i32x4* ssrc = (const i32x4*)(in_idx + j0);
    for (int ii = t; ii < CHUNK / 4; ii += 256) {
        i32x4 d = dsrc[ii];
#pragma unroll
        for (int q = 0; q < 4; ++q) atomicAdd(&lc[d[q] >> 7], 1);
    }
    __syncthreads();
    for (int i = t; i < NB; i += 256)
        lc[i] = atomicAdd(&cnt[k * NB + i], lc[i]);   // lc[i] := global base
    __syncthreads();
    for (int ii = t; ii < CHUNK / 4; ii += 256) {
        i32x4 d4 = dsrc[ii];
        i32x4 s4 = ssrc[ii];
#pragma unroll
        for (int q = 0; q < 4; ++q) {
            int d = d4[q];
            int b = d >> 7;
            int pos = atomicAdd(&lc[b], 1);
            if (pos < CAP)
                entries[(k * NB + b) * CAP + pos] =
                    ((unsigned)(d & 127) << 17) | (unsigned)s4[q];
        }
    }
}

// ---------------- conv: edge-dense MFMA tiles + fixed-point LDS scatter ------------
// 512 threads = 8 waves/block; wave w handles k = w, w+8, ...
// 3-stage gather pipeline: fragments for tile t+2 issued at top of tile t
// (round 6 showed 1-tile lookahead < L3 latency; more waves didn't help -> need ILP).
// Scatter rows derived from the eg registers via width-16 shuffles (no VMEM reload).
// launch_bounds(512,4): VGPR cap 128. NEVER request waves/EU the allocator can't
// meet: (256,5)->48 VGPR/140MB scratch (r3); (512,6)->40 VGPR/1.4GB scratch (r5).
__global__ __launch_bounds__(512, 4) void k_conv(
    const unsigned short* __restrict__ xb,    // [N][64] bf16
    const unsigned short* __restrict__ Wt,    // [27][cout=64][cin=64] bf16
    const int* __restrict__ cnt,              // [KK*NB] bucket counts
    const unsigned* __restrict__ entries,     // [KK*NB*CAP]: (dloc7<<17)|src17
    float* __restrict__ y,                    // [N][64] fp32
    float* __restrict__ sums)                 // [128]: sum, sumsq per channel
{
    __shared__ int ylds[MT * 64];             // 32768 B

    const int tid  = threadIdx.x;
    const int lane = tid & 63;
    const int wave = tid >> 6;                // 0..7
    const int quad = lane >> 4;
    const int l16  = lane & 15;
    const int blk  = blockIdx.x;
    const int i0   = blk << 7;

    for (int i = tid; i < MT * 64; i += 512) ylds[i] = 0;
    __syncthreads();

    const unsigned short* xq = xb + quad * 8;

    for (int k = wave; k < KK; k += 8) {
        const int bkt   = k * NB + blk;
        const int start = bkt * CAP;
        int E = cnt[bkt];
        E = E > CAP ? CAP : E;
        if (E == 0) continue;
        const int emax = E - 1;

        // B fragments straight from global Wt (221 KB total, L2-hot)
        bf16x8 bfr[4][2];
        const unsigned short* wk = Wt + k * (CC * CC) + l16 * CC + quad * 8;
#pragma unroll
        for (int nt = 0; nt < 4; ++nt) {
            bfr[nt][0] = *(const bf16x8*)(wk + nt * 16 * CC);
            bfr[nt][1] = *(const bf16x8*)(wk + nt * 16 * CC + 32);
        }

        const int ntile = (E + 31) >> 5;

        // ---- pipeline prologue: eg queue 4 deep, fragments 3 deep ----
        unsigned eA0 = entries[start + min(l16, emax)];
        unsigned eB0 = entries[start + min(16 + l16, emax)];
        bf16x8 fc[2][2], fn[2][2];
        {
            const unsigned short* p0 = xq + (eA0 & 0x1FFFFu) * CC;
            const unsigned short* p1 = xq + (eB0 & 0x1FFFFu) * CC;
            fc[0][0] = *(const bf16x8*)p0;
            fc[0][1] = *(const bf16x8*)(p0 + 32);
            fc[1][0] = *(const bf16x8*)p1;
            fc[1][1] = *(const bf16x8*)(p1 + 32);
        }
        unsigned eA1 = entries[start + min(32 + l16, emax)];
        unsigned eB1 = entries[start + min(48 + l16, emax)];
        {
            const unsigned short* p0 = xq + (eA1 & 0x1FFFFu) * CC;
            const unsigned short* p1 = xq + (eB1 & 0x1FFFFu) * CC;
            fn[0][0] = *(const bf16x8*)p0;
            fn[0][1] = *(const bf16x8*)(p0 + 32);
            fn[1][0] = *(const bf16x8*)p1;
            fn[1][1] = *(const bf16x8*)(p1 + 32);
        }
        unsigned eA2 = entries[start + min(64 + l16, emax)];
        unsigned eB2 = entries[start + min(80 + l16, emax)];

        for (int t = 0; t < ntile; ++t) {
            const int tb = t * 32;
            // scatter rows for THIS tile from resident eg regs (width-16 shuffle)
            unsigned dp[2][4];
#pragma unroll
            for (int rr = 0; rr < 4; ++rr) {
                dp[0][rr] = (unsigned)__shfl((int)eA0, quad * 4 + rr, 16);
                dp[1][rr] = (unsigned)__shfl((int)eB0, quad * 4 + rr, 16);
            }
            // issue gather for tile t+2 from resident indices
            bf16x8 fp[2][2];
            {
                const unsigned short* p0 = xq + (eA2 & 0x1FFFFu) * CC;
                const unsigned short* p1 = xq + (eB2 & 0x1FFFFu) * CC;
                fp[0][0] = *(const bf16x8*)p0;
                fp[0][1] = *(const bf16x8*)(p0 + 32);
                fp[1][0] = *(const bf16x8*)p1;
                fp[1][1] = *(const bf16x8*)(p1 + 32);
            }
            // prefetch indices for tile t+3
            unsigned eA3 = entries[start + min(tb + 96 + l16, emax)];
            unsigned eB3 = entries[start + min(tb + 112 + l16, emax)];

            f32x4 acc[2][4];
#pragma unroll
            for (int mt = 0; mt < 2; ++mt)
#pragma unroll
                for (int nt = 0; nt < 4; ++nt) acc[mt][nt] = (f32x4){0.f, 0.f, 0.f, 0.f};
            __builtin_amdgcn_s_setprio(1);
#pragma unroll
            for (int mt = 0; mt < 2; ++mt)
#pragma unroll
                for (int nt = 0; nt < 4; ++nt) {
                    acc[mt][nt] = __builtin_amdgcn_mfma_f32_16x16x32_bf16(
                        fc[mt][0], bfr[nt][0], acc[mt][nt], 0, 0, 0);
                    acc[mt][nt] = __builtin_amdgcn_mfma_f32_16x16x32_bf16(
                        fc[mt][1], bfr[nt][1], acc[mt][nt], 0, 0, 0);
                }
            __builtin_amdgcn_s_setprio(0);

            // scatter: 32 native ds_add_u32 per lane per tile (fixed-point, swizzled)
#pragma unroll
            for (int mt = 0; mt < 2; ++mt)
#pragma unroll
                for (int rr = 0; rr < 4; ++rr) {
                    int slot = tb + mt * 16 + quad * 4 + rr;
                    if (slot < E) {
                        int row = (int)(dp[mt][rr] >> 17);
                        int xv = (row & 1) << 4;
                        unsigned* yp = (unsigned*)&ylds[row * 64 + l16];
                        atomicAdd(yp + (0 ^ xv),  (unsigned)f2fix(acc[mt][0][rr]));
                        atomicAdd(yp + (16 ^ xv), (unsigned)f2fix(acc[mt][1][rr]));
                        atomicAdd(yp + (32 ^ xv), (unsigned)f2fix(acc[mt][2][rr]));
                        atomicAdd(yp + (48 ^ xv), (unsigned)f2fix(acc[mt][3][rr]));
                    }
                }
            // rotate pipeline
            fc[0][0] = fn[0][0]; fc[0][1] = fn[0][1];
            fc[1][0] = fn[1][0]; fc[1][1] = fn[1][1];
            fn[0][0] = fp[0][0]; fn[0][1] = fp[0][1];
            fn[1][0] = fp[1][0]; fn[1][1] = fp[1][1];
            eA0 = eA1; eB0 = eB1;
            eA1 = eA2; eB1 = eB2;
            eA2 = eA3; eB2 = eB3;
        }
    }
    __syncthreads();

    // epilogue: write y + fused BN partial sums (ylds reused as scratch after reads)
    const int col = tid & 63;
    const int rg  = tid >> 6;                 // 0..7 -> 16 rows each
    float s = 0.f, q = 0.f;
#pragma unroll
    for (int i = 0; i < 16; ++i) {
        int row = rg * 16 + i;
        float v = (float)ylds[row * 64 + (col ^ ((row & 1) << 4))] * FPINV;
        int gr = i0 + row;
        if (gr < NPTS) y[(long)gr * CC + col] = v;
        s += v; q += v * v;
    }
    __syncthreads();                      // all ylds reads done
    float* ps = (float*)ylds;
    ps[rg * 128 + col] = s;
    ps[rg * 128 + 64 + col] = q;
    __syncthreads();
    if (tid < 128) {
        int which = tid >> 6, c = tid & 63;
        float a = 0.f;
#pragma unroll
        for (int wv = 0; wv < 8; ++wv) a += ps[wv * 128 + which * 64 + c];
        atomicAdd(&sums[which * 64 + c], a);
    }
}

// ---------------- a1 = bf16(relu(y*s + b)) with inline BN finalize ----------------
__global__ void k_apply(const float* __restrict__ y, const float* __restrict__ sums,
                        const float* __restrict__ gamma, const float* __restrict__ beta,
                        unsigned short* __restrict__ ab) {
    __shared__ float sb[128];
    int t = threadIdx.x;
    if (t < 64) {
        float mu  = sums[t] * (1.0f / NPTS);
        float var = sums[t + 64] * (1.0f / NPTS) - mu * mu;
        float s = gamma[t] * rsqrtf(var + EPSBN);
        sb[t] = s;
        sb[t + 64] = beta[t] - mu * s;
    }
    __syncthreads();
    int id = blockIdx.x * 256 + t;
    f32x4 v = ((const f32x4*)y)[id];
    int c0 = (id * 4) & 63;
    u16x4 o;
#pragma unroll
    for (int j = 0; j < 4; ++j) {
        float r = fmaxf(v[j] * sb[c0 + j] + sb[64 + c0 + j], 0.f);
        o[j] = f2bf(r);
    }
    ((u16x4*)ab)[id] = o;
}

// ---------------- out = relu(y*s + b + x) with inline BN finalize ----------------
__global__ void k_final(const float* __restrict__ y, const float* __restrict__ x,
                        const float* __restrict__ sums,
                        const float* __restrict__ gamma, const float* __restrict__ beta,
                        float* __restrict__ out) {
    __shared__ float sb[128];
    int t = threadIdx.x;
    if (t < 64) {
        float mu  = sums[t] * (1.0f / NPTS);
        float var = sums[t + 64] * (1.0f / NPTS) - mu * mu;
        float s = gamma[t] * rsqrtf(var + EPSBN);
        sb[t] = s;
        sb[t + 64] = beta[t] - mu * s;
    }
    __syncthreads();
    int id = blockIdx.x * 256 + t;
    f32x4 v  = ((const f32x4*)y)[id];
    f32x4 xv = ((const f32x4*)x)[id];
    int c0 = (id * 4) & 63;
    f32x4 o;
#pragma unroll
    for (int j = 0; j < 4; ++j)
        o[j] = fmaxf(v[j] * sb[c0 + j] + sb[64 + c0 + j] + xv[j], 0.f);
    ((f32x4*)out)[id] = o;
}

extern "C" void kernel_launch(void* const* d_in, const int* in_sizes, int n_in,
                              void* d_out, int out_size, void* d_ws, size_t ws_size,
                              hipStream_t stream) {
    const float* x      = (const float*)d_in[0];
    // d_in[1] = norm_points (unused by the reference math)
    const float* W1     = (const float*)d_in[2];
    const float* gamma1 = (const float*)d_in[3];
    const float* beta1  = (const float*)d_in[4];
    const float* W2     = (const float*)d_in[5];
    const float* gamma2 = (const float*)d_in[6];
    const float* beta2  = (const float*)d_in[7];
    const int* in_idx   = (const int*)d_in[8];
    const int* out_idx  = (const int*)d_in[9];
    float* out = (float*)d_out;

    char* w = (char*)d_ws;
    size_t off = 0;
    auto alloc = [&](size_t bytes) -> char* {
        off = (off + 255) & ~(size_t)255;
        char* p = w + off;
        off += bytes;
        return p;
    };
    int*   cnt       = (int*)     alloc((size_t)KK * NB * 4);
    float* sums      = (float*)   alloc(256 * 4);   // [0:128) layer1, [128:256) layer2
    unsigned* entries = (unsigned*)alloc((size_t)KK * NB * CAP * 4);
    unsigned short* xbf = (unsigned short*)alloc((size_t)NPTS * CC * 2);
    unsigned short* Wt1 = (unsigned short*)alloc((size_t)KK * CC * CC * 2);
    unsigned short* Wt2 = (unsigned short*)alloc((size_t)KK * CC * CC * 2);
    float* y = (float*)alloc((size_t)NPTS * CC * 4);

    // zero cnt + sums in one shot (contiguous allocations incl. alignment gap)
    size_t zlen = (size_t)((char*)(sums + 256) - (char*)cnt);
    hipMemsetAsync(cnt, 0, zlen, stream);

    k_prep<<<XBLK + WBLK, 256, 0, stream>>>(x, W1, W2, xbf, Wt1, Wt2);
    k_part<<<NCH, 256, 0, stream>>>(out_idx, in_idx, cnt, entries);

    k_conv<<<NB, 512, 0, stream>>>(xbf, Wt1, cnt, entries, y, sums);
    k_apply<<<NPTS * CC / 1024, 256, 0, stream>>>(y, sums, gamma1, beta1, xbf);  // a1 -> xbf
    k_conv<<<NB, 512, 0, stream>>>(xbf, Wt2, cnt, entries, y, sums + 128);
    k_final<<<NPTS * CC / 1024, 256, 0, stream>>>(y, x, sums + 128, gamma2, beta2, out);
}